// Round 2
// baseline (517.439 us; speedup 1.0000x reference)
//
#include <hip/hip_runtime.h>

// PosEncoding: out[n][d] = (d even ? sin : cos)(positions[n] * w_k[d]),
// zeroed where positions[n] == 0.  N = 1e6, D = 128.
//
// Memory-bound: 512 MB write-only output. Layout: 32 threads/row, float4
// (16B) nontemporal store per thread -> wave writes 1 KiB contiguous.
// w_k[2k]==w_k[2k+1], so each thread computes 2 angles -> sin/cos pairs.

#define D_WORD 128

// clang native vector type (HIP's float4 is a struct; the nontemporal
// builtin only takes scalar/native-vector pointers)
typedef float f32x4 __attribute__((ext_vector_type(4)));

__global__ __launch_bounds__(256) void posenc_kernel(
    const float* __restrict__ positions,
    const float* __restrict__ w_k,
    float* __restrict__ out,
    int n_pos) {
    int tid  = blockIdx.x * blockDim.x + threadIdx.x;
    int row  = tid >> 5;         // 32 threads per row
    int lane = tid & 31;
    if (row >= n_pos) return;

    int d4 = lane << 2;          // 0,4,...,124 — 16B aligned into w_k and out row
    float p = positions[row];    // broadcast load across 32 lanes

    f32x4 w = *(const f32x4*)(w_k + d4);   // w.x==w.y (freq 2k), w.z==w.w (freq 2k+1)

    // hardware v_sin/v_cos take REVOLUTIONS; reduce manually (angle up to 8192 rad)
    const float inv2pi = 0.15915494309189535f;
    float r0 = p * w.x * inv2pi;
    float r1 = p * w.z * inv2pi;
    r0 = r0 - floorf(r0);
    r1 = r1 - floorf(r1);

    f32x4 o;
    o.x = __builtin_amdgcn_sinf(r0);   // d4+0 even -> sin
    o.y = __builtin_amdgcn_cosf(r0);   // d4+1 odd  -> cos
    o.z = __builtin_amdgcn_sinf(r1);   // d4+2 even -> sin
    o.w = __builtin_amdgcn_cosf(r1);   // d4+3 odd  -> cos

    if (p == 0.0f) { o = (f32x4){0.f, 0.f, 0.f, 0.f}; }

    __builtin_nontemporal_store(o, (f32x4*)(out + (size_t)row * D_WORD + d4));
}

extern "C" void kernel_launch(void* const* d_in, const int* in_sizes, int n_in,
                              void* d_out, int out_size, void* d_ws, size_t ws_size,
                              hipStream_t stream) {
    const float* positions = (const float*)d_in[0];
    const float* w_k       = (const float*)d_in[1];
    float* out             = (float*)d_out;
    int n_pos = in_sizes[0];               // 1,000,000

    // 32 threads per row, 256 threads per block => 8 rows per block
    long long total_threads = (long long)n_pos * 32;
    int block = 256;
    int grid  = (int)((total_threads + block - 1) / block);

    posenc_kernel<<<grid, block, 0, stream>>>(positions, w_k, out, n_pos);
}